// Round 3
// baseline (807.759 us; speedup 1.0000x reference)
//
#include <hip/hip_runtime.h>
#include <hip/hip_bf16.h>
#include <stdint.h>

#define S_LEN 4096
#define NHEAD 8
#define L2E   1.44269504088896340736f

typedef __attribute__((ext_vector_type(8))) short bf16x8;
typedef __attribute__((ext_vector_type(4))) float f32x4;
typedef unsigned short u16;
typedef unsigned int   u32;

#define MFMA16(a,b,c) __builtin_amdgcn_mfma_f32_16x16x32_bf16((a),(b),(c),0,0,0)
#define EXP2F(x) __builtin_amdgcn_exp2f((x))

__device__ __forceinline__ void gl_lds16(const void* g, void* l) {
  __builtin_amdgcn_global_load_lds((const __attribute__((address_space(1))) void*)g,
                                   (__attribute__((address_space(3))) void*)l, 16, 0, 0);
}

// ws layout (bytes)
#define WS_A1HI 0u
#define WS_A1LO (4u<<20)
#define WS_A2HI (8u<<20)
#define WS_A2LO (12u<<20)
#define WS_VHI  (16u<<20)
#define WS_VLO  (20u<<20)
#define WS_BM   (24u<<20)
#define WS_INVL (26u<<20)
#define WS_EXPB (28u<<20)

// ---- PK1: pack mask (1,1,S,S) int32 -> bitmask bmT[s/32][t] (bit = masked) ----
__global__ void pk_mask(const int* __restrict__ mask, u32* __restrict__ bmT) {
  const int sb = blockIdx.x >> 4;                   // 0..127 (s/32)
  const int t  = (blockIdx.x & 15) * 256 + threadIdx.x;
  u32 w = 0;
  #pragma unroll
  for (int j = 0; j < 32; ++j)
    w |= (mask[(size_t)(sb * 32 + j) * S_LEN + t] != 0 ? 1u : 0u) << j;
  bmT[sb * S_LEN + t] = w;
}

// ---- PK2: A1 fp32 -> bf16 hi/lo, same layout ----
__global__ void pk_split(const float* __restrict__ src, u16* __restrict__ hi, u16* __restrict__ lo) {
  const int i = blockIdx.x * 256 + threadIdx.x;     // x4 floats
  float4 x = ((const float4*)src)[i];
  ushort4 hv, lv;
  #pragma unroll
  for (int j = 0; j < 4; ++j) {
    float xv = ((const float*)&x)[j];
    __hip_bfloat16 hb = __float2bfloat16(xv);
    float hf = __bfloat162float(hb);
    __hip_bfloat16 lb = __float2bfloat16(xv - hf);
    ((u16*)&hv)[j] = *(u16*)&hb;
    ((u16*)&lv)[j] = *(u16*)&lb;
  }
  ((ushort4*)hi)[i] = hv;
  ((ushort4*)lo)[i] = lv;
}

// ---- PK3: 64x64 tile transpose + hi/lo split + XOR pre-swizzle ----
// element (r,c) of transposed tile lives at o = r*64 + (c ^ ((r&7)<<3))
__global__ void pk_tsplit(const float* __restrict__ src, u16* __restrict__ hi, u16* __restrict__ lo,
                          int chunk_stride, int row_stride) {
  const int h = blockIdx.x >> 6, ci = blockIdx.x & 63;
  const float* base = src + (size_t)h * (S_LEN * 64) + (size_t)ci * chunk_stride;
  __shared__ float tile[64][65];
  const int jr = threadIdx.x & 63, ir = threadIdx.x >> 6;
  #pragma unroll
  for (int p = 0; p < 16; ++p) {
    int i = p * 4 + ir;
    tile[i][jr] = base[(size_t)i * row_stride + jr];
  }
  __syncthreads();
  const size_t ob = (size_t)(h * 64 + ci) * 4096;
  #pragma unroll
  for (int p = 0; p < 16; ++p) {
    int o = p * 256 + threadIdx.x;
    int r = o >> 6;
    int cc = (o & 63) ^ ((r & 7) << 3);
    float xv = tile[cc][r];
    __hip_bfloat16 hb = __float2bfloat16(xv);
    float hf = __bfloat162float(hb);
    __hip_bfloat16 lb = __float2bfloat16(xv - hf);
    hi[ob + o] = *(u16*)&hb;
    lo[ob + o] = *(u16*)&lb;
  }
}

// ---- main fused kernel (single pass, no-max softmax):
//      scores(bf16x3 MFMA) -> exp2 -> {row-sum regs, exp->ws bf16, PV unnormalized}.
//      WG = 512 thr (8 waves, 4s x 2t), 128 s-rows of one head, TB=64 t per chunk,
//      double-buffered LDS staging (T3-minimal 2-phase). ----
__launch_bounds__(512, 2)
__global__ void fattn_main(const u16* __restrict__ a1hi, const u16* __restrict__ a1lo,
                           const u16* __restrict__ a2hi, const u16* __restrict__ a2lo,
                           const u16* __restrict__ vhi,  const u16* __restrict__ vlo,
                           const u32* __restrict__ bmT,  u16* __restrict__ expb,
                           float* __restrict__ invl,     float* __restrict__ dout) {
  const int h   = blockIdx.x & 7;     // head == XCD
  const int sb  = blockIdx.x >> 3;    // 0..31
  const int tid = threadIdx.x;
  const int w = tid >> 6, lane = tid & 63;
  const int g = lane >> 4, c = lane & 15;
  const int wsr = w >> 1;             // s-quarter (0..3)
  const int wth = w & 1;              // t-half (0/1)
  const int sbase = sb * 128 + wsr * 32;
  const int sb32  = sb * 4 + wsr;

  __shared__ __align__(16) char smem[87040];
  // dbuf: smem + buf*32768 : {a2h 8K, a2l 8K, vh 8K, vl 8K}
  u16*   atb = (u16*)(smem + 65536);      // [8 waves][32 s][40 t] bf16 = 20480 B
  float* mll = (float*)(smem + 86016);    // [8][32]

  // A1 fragments in regs: [mt][kk][hi/lo]
  bf16x8 a1f[2][2][2];
  #pragma unroll
  for (int mt = 0; mt < 2; ++mt)
    #pragma unroll
    for (int kk = 0; kk < 2; ++kk) {
      size_t base = (size_t)(h * S_LEN + sbase + mt * 16 + c) * 64 + kk * 32 + g * 8;
      a1f[mt][kk][0] = *(const bf16x8*)(a1hi + base);
      a1f[mt][kk][1] = *(const bf16x8*)(a1lo + base);
    }

  float rl[2][4];
  f32x4 oacc[2][4];
  #pragma unroll
  for (int mt = 0; mt < 2; ++mt) {
    #pragma unroll
    for (int r = 0; r < 4; ++r) rl[mt][r] = 0.f;
    #pragma unroll
    for (int dt = 0; dt < 4; ++dt) oacc[mt][dt] = (f32x4){0.f, 0.f, 0.f, 0.f};
  }

  const u32* bmrow = bmT + (size_t)sb32 * S_LEN;

  auto stage_all = [&](int bufi, int ci) {
    const size_t tb = (size_t)(h * 64 + ci) * 4096;
    char* lb = smem + bufi * 32768;
    const int off = w * 1024 + lane * 16;
    gl_lds16((const char*)(a2hi + tb) + off, lb +         w * 1024);
    gl_lds16((const char*)(a2lo + tb) + off, lb +  8192 + w * 1024);
    gl_lds16((const char*)(vhi  + tb) + off, lb + 16384 + w * 1024);
    gl_lds16((const char*)(vlo  + tb) + off, lb + 24576 + w * 1024);
  };

  stage_all(0, 0);
  __syncthreads();

  #pragma unroll 1
  for (int ci = 0; ci < 64; ++ci) {
    if (ci < 63) stage_all((ci + 1) & 1, ci + 1);   // prefetch next tile

    const u16* base = (const u16*)(smem + (ci & 1) * 32768);  // a2h; +4096 a2l; +8192 vh; +12288 vl

    // ---- scores ----
    f32x4 acc[2][2];
    #pragma unroll
    for (int mt = 0; mt < 2; ++mt)
      #pragma unroll
      for (int nt = 0; nt < 2; ++nt) acc[mt][nt] = (f32x4){0.f, 0.f, 0.f, 0.f};
    #pragma unroll
    for (int kk = 0; kk < 2; ++kk)
      #pragma unroll
      for (int nt = 0; nt < 2; ++nt) {
        int eb = (wth * 32 + nt * 16 + c) * 64 + ((kk * 32 + g * 8) ^ ((c & 7) << 3));
        bf16x8 bh = *(const bf16x8*)(base + eb);
        bf16x8 bl = *(const bf16x8*)(base + 4096 + eb);
        #pragma unroll
        for (int mt = 0; mt < 2; ++mt) {
          acc[mt][nt] = MFMA16(a1f[mt][kk][0], bh, acc[mt][nt]);   // hi*hi
          acc[mt][nt] = MFMA16(a1f[mt][kk][0], bl, acc[mt][nt]);   // hi*lo
          acc[mt][nt] = MFMA16(a1f[mt][kk][1], bh, acc[mt][nt]);   // lo*hi
        }
      }

    // ---- mask + exp2 + row-sum ----
    const u32 mw0 = bmrow[ci * 64 + wth * 32 + c];
    const u32 mw1 = bmrow[ci * 64 + wth * 32 + 16 + c];
    float e[2][2][4];
    #pragma unroll
    for (int mt = 0; mt < 2; ++mt)
      #pragma unroll
      for (int nt = 0; nt < 2; ++nt) {
        const u32 mwv = nt ? mw1 : mw0;
        #pragma unroll
        for (int r = 0; r < 4; ++r) {
          float ex = EXP2F(acc[mt][nt][r] * L2E);
          float ev = ((mwv >> (mt * 16 + g * 4 + r)) & 1u) ? 0.f : ex;
          e[mt][nt][r] = ev;
          rl[mt][r] += ev;
        }
      }

    // ---- transpose exp -> bf16 via per-wave LDS buf ----
    u16* my = atb + w * 1280;
    #pragma unroll
    for (int mt = 0; mt < 2; ++mt)
      #pragma unroll
      for (int nt = 0; nt < 2; ++nt)
        #pragma unroll
        for (int r = 0; r < 4; ++r) {
          __hip_bfloat16 hb = __float2bfloat16(e[mt][nt][r]);
          my[(mt * 16 + g * 4 + r) * 40 + nt * 16 + c] = *(u16*)&hb;
        }
    bf16x8 af[2];
    #pragma unroll
    for (int mt = 0; mt < 2; ++mt)
      af[mt] = *(const bf16x8*)(my + (mt * 16 + c) * 40 + g * 8);

    // ---- stream unnormalized exp (bf16) to ws, 64B segments per (g-quad) ----
    #pragma unroll
    for (int mt = 0; mt < 2; ++mt)
      *(bf16x8*)(expb + (size_t)(h * S_LEN + sbase + mt * 16 + c) * S_LEN
                       + ci * 64 + wth * 32 + g * 8) = af[mt];

    // ---- PV (unnormalized) ----
    #pragma unroll
    for (int dt = 0; dt < 4; ++dt) {
      int ve = (dt * 16 + c) * 64 + ((wth * 32 + g * 8) ^ ((c & 7) << 3));
      bf16x8 bvh = *(const bf16x8*)(base + 8192 + ve);
      bf16x8 bvl = *(const bf16x8*)(base + 12288 + ve);
      #pragma unroll
      for (int mt = 0; mt < 2; ++mt) {
        oacc[mt][dt] = MFMA16(af[mt], bvh, oacc[mt][dt]);
        oacc[mt][dt] = MFMA16(af[mt], bvl, oacc[mt][dt]);
      }
    }

    __syncthreads();   // next buffer staged + everyone done reading cur
  }

  // ---- epilogue: reduce l, write invl, normalize oacc, merge t-halves, store ----
  #pragma unroll
  for (int mt = 0; mt < 2; ++mt)
    #pragma unroll
    for (int r = 0; r < 4; ++r) {
      float s = rl[mt][r];
      #pragma unroll
      for (int off = 1; off < 16; off <<= 1) s += __shfl_xor(s, off);
      rl[mt][r] = s;                       // per-t-half row sum (all c lanes)
    }
  __syncthreads();
  if (c == 0) {
    #pragma unroll
    for (int mt = 0; mt < 2; ++mt)
      #pragma unroll
      for (int r = 0; r < 4; ++r)
        mll[w * 32 + mt * 16 + g * 4 + r] = rl[mt][r];
  }
  __syncthreads();
  float inv[2][4];
  #pragma unroll
  for (int mt = 0; mt < 2; ++mt)
    #pragma unroll
    for (int r = 0; r < 4; ++r) {
      float tot = rl[mt][r] + mll[(w ^ 1) * 32 + mt * 16 + g * 4 + r];
      inv[mt][r] = 1.0f / tot;
    }
  if (wth == 0 && c == 0) {
    #pragma unroll
    for (int mt = 0; mt < 2; ++mt)
      #pragma unroll
      for (int r = 0; r < 4; ++r)
        invl[h * S_LEN + sbase + mt * 16 + g * 4 + r] = inv[mt][r];
  }
  #pragma unroll
  for (int mt = 0; mt < 2; ++mt)
    #pragma unroll
    for (int dt = 0; dt < 4; ++dt)
      #pragma unroll
      for (int r = 0; r < 4; ++r)
        oacc[mt][dt][r] *= inv[mt][r];

  __syncthreads();
  float* outx = (float*)smem;            // [4 wsr][32][66] f32 = 33792 B, aliases staging
  if (wth == 1) {
    #pragma unroll
    for (int mt = 0; mt < 2; ++mt)
      #pragma unroll
      for (int dt = 0; dt < 4; ++dt)
        #pragma unroll
        for (int r = 0; r < 4; ++r)
          outx[wsr * 2112 + (mt * 16 + g * 4 + r) * 66 + dt * 16 + c] = oacc[mt][dt][r];
  }
  __syncthreads();
  if (wth == 0) {
    #pragma unroll
    for (int mt = 0; mt < 2; ++mt)
      #pragma unroll
      for (int dt = 0; dt < 4; ++dt)
        #pragma unroll
        for (int r = 0; r < 4; ++r) {
          float vv = oacc[mt][dt][r] + outx[wsr * 2112 + (mt * 16 + g * 4 + r) * 66 + dt * 16 + c];
          int s = sbase + mt * 16 + g * 4 + r;
          dout[(size_t)(h * S_LEN + s) * 64 + dt * 16 + c] = vv;
        }
  }
}

// ---- normalize: attn[row][t] = f32(expb[row][t]) * invl[row]; one row per block ----
__global__ void attn_norm(const u16* __restrict__ expb, const float* __restrict__ invl,
                          float* __restrict__ aout) {
  const int row = blockIdx.x;                 // h*4096 + s
  const float iv = invl[row];
  const u16* src = expb + (size_t)row * S_LEN;
  float* dst = aout + (size_t)row * S_LEN;
  const int t0 = threadIdx.x * 16;
  bf16x8 v0 = *(const bf16x8*)(src + t0);
  bf16x8 v1 = *(const bf16x8*)(src + t0 + 8);
  float4 o[4];
  #pragma unroll
  for (int j = 0; j < 8; ++j) {
    ((float*)o)[j]     = __uint_as_float(((u32)(u16)v0[j]) << 16) * iv;
    ((float*)o)[j + 8] = __uint_as_float(((u32)(u16)v1[j]) << 16) * iv;
  }
  #pragma unroll
  for (int k = 0; k < 4; ++k)
    ((float4*)(dst + t0))[k] = o[k];
}

extern "C" void kernel_launch(void* const* d_in, const int* in_sizes, int n_in,
                              void* d_out, int out_size, void* d_ws, size_t ws_size,
                              hipStream_t stream) {
  (void)in_sizes; (void)n_in; (void)out_size; (void)ws_size;
  const float* v    = (const float*)d_in[0];
  const float* A1   = (const float*)d_in[1];
  const float* A2   = (const float*)d_in[2];
  const int*   mask = (const int*)d_in[3];
  float* out = (float*)d_out;
  char* ws = (char*)d_ws;

  u16* a1hi = (u16*)(ws + WS_A1HI);
  u16* a1lo = (u16*)(ws + WS_A1LO);
  u16* a2hi = (u16*)(ws + WS_A2HI);
  u16* a2lo = (u16*)(ws + WS_A2LO);
  u16* vhi  = (u16*)(ws + WS_VHI);
  u16* vlo  = (u16*)(ws + WS_VLO);
  u32* bmT  = (u32*)(ws + WS_BM);
  float* invl = (float*)(ws + WS_INVL);
  u16* expb = (u16*)(ws + WS_EXPB);

  float* aout = out + (size_t)NHEAD * S_LEN * 64;

  pk_mask  <<<2048, 256, 0, stream>>>(mask, bmT);
  pk_split <<<2048, 256, 0, stream>>>(A1, a1hi, a1lo);
  pk_tsplit<<<512,  256, 0, stream>>>(A2, a2hi, a2lo, 64, 4096);   // A2[f][t] -> [t][f]
  pk_tsplit<<<512,  256, 0, stream>>>(v,  vhi,  vlo,  4096, 64);   // v[t][d]  -> [d][t]
  fattn_main<<<256, 512, 0, stream>>>(a1hi, a1lo, a2hi, a2lo, vhi, vlo, bmT, expb, invl, out);
  attn_norm<<<NHEAD * S_LEN, 256, 0, stream>>>(expb, invl, aout);
}

// Round 4
// 794.255 us; speedup vs baseline: 1.0170x; 1.0170x over previous
//
#include <hip/hip_runtime.h>
#include <hip/hip_bf16.h>
#include <stdint.h>

#define S_LEN 4096
#define NHEAD 8
#define L2E   1.44269504088896340736f

typedef __attribute__((ext_vector_type(8))) short bf16x8;
typedef __attribute__((ext_vector_type(4))) float f32x4;
typedef unsigned short u16;
typedef unsigned int   u32;

#define MFMA16(a,b,c) __builtin_amdgcn_mfma_f32_16x16x32_bf16((a),(b),(c),0,0,0)
#define EXP2F(x) __builtin_amdgcn_exp2f((x))

__device__ __forceinline__ void gl_lds16(const void* g, void* l) {
  __builtin_amdgcn_global_load_lds((const __attribute__((address_space(1))) void*)g,
                                   (__attribute__((address_space(3))) void*)l, 16, 0, 0);
}

__device__ __forceinline__ short f2bf(float x) {
  __hip_bfloat16 h = __float2bfloat16(x);
  return *(short*)&h;
}

// ws layout (bytes)
#define WS_A1HI 0u
#define WS_A1LO (4u<<20)
#define WS_A2HI (8u<<20)
#define WS_A2LO (12u<<20)
#define WS_VHI  (16u<<20)
#define WS_VLO  (20u<<20)
#define WS_BM   (24u<<20)
#define WS_INVL (26u<<20)

// ---- PK1: pack mask (1,1,S,S) int32 -> bitmask bmT[s/32][t] (bit = masked) ----
__global__ void pk_mask(const int* __restrict__ mask, u32* __restrict__ bmT) {
  const int sb = blockIdx.x >> 4;                   // 0..127 (s/32)
  const int t  = (blockIdx.x & 15) * 256 + threadIdx.x;
  u32 w = 0;
  #pragma unroll
  for (int j = 0; j < 32; ++j)
    w |= (mask[(size_t)(sb * 32 + j) * S_LEN + t] != 0 ? 1u : 0u) << j;
  bmT[sb * S_LEN + t] = w;
}

// ---- PK2: A1 fp32 -> bf16 hi/lo, same layout ----
__global__ void pk_split(const float* __restrict__ src, u16* __restrict__ hi, u16* __restrict__ lo) {
  const int i = blockIdx.x * 256 + threadIdx.x;     // x4 floats
  float4 x = ((const float4*)src)[i];
  ushort4 hv, lv;
  #pragma unroll
  for (int j = 0; j < 4; ++j) {
    float xv = ((const float*)&x)[j];
    __hip_bfloat16 hb = __float2bfloat16(xv);
    float hf = __bfloat162float(hb);
    __hip_bfloat16 lb = __float2bfloat16(xv - hf);
    ((u16*)&hv)[j] = *(u16*)&hb;
    ((u16*)&lv)[j] = *(u16*)&lb;
  }
  ((ushort4*)hi)[i] = hv;
  ((ushort4*)lo)[i] = lv;
}

// ---- PK3: 64x64 tile transpose + hi/lo split + XOR pre-swizzle ----
// element (r,c) of transposed tile lives at o = r*64 + (c ^ ((r&7)<<3))
__global__ void pk_tsplit(const float* __restrict__ src, u16* __restrict__ hi, u16* __restrict__ lo,
                          int chunk_stride, int row_stride) {
  const int h = blockIdx.x >> 6, ci = blockIdx.x & 63;
  const float* base = src + (size_t)h * (S_LEN * 64) + (size_t)ci * chunk_stride;
  __shared__ float tile[64][65];
  const int jr = threadIdx.x & 63, ir = threadIdx.x >> 6;
  #pragma unroll
  for (int p = 0; p < 16; ++p) {
    int i = p * 4 + ir;
    tile[i][jr] = base[(size_t)i * row_stride + jr];
  }
  __syncthreads();
  const size_t ob = (size_t)(h * 64 + ci) * 4096;
  #pragma unroll
  for (int p = 0; p < 16; ++p) {
    int o = p * 256 + threadIdx.x;
    int r = o >> 6;
    int cc = (o & 63) ^ ((r & 7) << 3);
    float xv = tile[cc][r];
    __hip_bfloat16 hb = __float2bfloat16(xv);
    float hf = __bfloat162float(hb);
    __hip_bfloat16 lb = __float2bfloat16(xv - hf);
    hi[ob + o] = *(u16*)&hb;
    lo[ob + o] = *(u16*)&lb;
  }
}

// ---- K2 (pass 1): scores (bf16x3 MFMA, identical chain to K3) -> exp2 -> row sums -> invl.
//      No max-tracking (scores bounded; exp2 safe in fp32). ----
__launch_bounds__(512, 2)
__global__ void fattn_pass1(const u16* __restrict__ a1hi, const u16* __restrict__ a1lo,
                            const u16* __restrict__ a2hi, const u16* __restrict__ a2lo,
                            const u32* __restrict__ bmT,  float* __restrict__ invl) {
  const int h   = blockIdx.x & 7;     // head == XCD affinity heuristic
  const int sb  = blockIdx.x >> 3;    // 0..31
  const int tid = threadIdx.x;
  const int w = tid >> 6, lane = tid & 63;
  const int g = lane >> 4, c = lane & 15;
  const int wsr = w >> 1;             // s-quarter (0..3)
  const int wth = w & 1;              // t-half (0/1)
  const int sbase = sb * 128 + wsr * 32;
  const int sb32  = sb * 4 + wsr;

  __shared__ __align__(16) char smem[33792];   // dbuf 2x16K {a2h 8K, a2l 8K} + mll 1K
  float* mll = (float*)(smem + 32768);

  bf16x8 a1f[2][2][2];
  #pragma unroll
  for (int mt = 0; mt < 2; ++mt)
    #pragma unroll
    for (int kk = 0; kk < 2; ++kk) {
      size_t base = (size_t)(h * S_LEN + sbase + mt * 16 + c) * 64 + kk * 32 + g * 8;
      a1f[mt][kk][0] = *(const bf16x8*)(a1hi + base);
      a1f[mt][kk][1] = *(const bf16x8*)(a1lo + base);
    }

  float rl[2][4];
  #pragma unroll
  for (int mt = 0; mt < 2; ++mt)
    #pragma unroll
    for (int r = 0; r < 4; ++r) rl[mt][r] = 0.f;

  const u32* bmrow = bmT + (size_t)sb32 * S_LEN;

  auto stage2 = [&](int bufi, int ci) {
    const size_t tb = (size_t)(h * 64 + ci) * 4096;
    char* lb = smem + bufi * 16384;
    const int off = w * 1024 + lane * 16;
    gl_lds16((const char*)(a2hi + tb) + off, lb +        w * 1024);
    gl_lds16((const char*)(a2lo + tb) + off, lb + 8192 + w * 1024);
  };

  stage2(0, 0);
  __syncthreads();

  #pragma unroll 1
  for (int ci = 0; ci < 64; ++ci) {
    if (ci < 63) stage2((ci + 1) & 1, ci + 1);

    const u16* base = (const u16*)(smem + (ci & 1) * 16384);

    f32x4 acc[2][2];
    #pragma unroll
    for (int mt = 0; mt < 2; ++mt)
      #pragma unroll
      for (int nt = 0; nt < 2; ++nt) acc[mt][nt] = (f32x4){0.f, 0.f, 0.f, 0.f};
    #pragma unroll
    for (int kk = 0; kk < 2; ++kk)
      #pragma unroll
      for (int nt = 0; nt < 2; ++nt) {
        int eb = (wth * 32 + nt * 16 + c) * 64 + ((kk * 32 + g * 8) ^ ((c & 7) << 3));
        bf16x8 bh = *(const bf16x8*)(base + eb);
        bf16x8 bl = *(const bf16x8*)(base + 4096 + eb);
        #pragma unroll
        for (int mt = 0; mt < 2; ++mt) {
          acc[mt][nt] = MFMA16(a1f[mt][kk][0], bh, acc[mt][nt]);
          acc[mt][nt] = MFMA16(a1f[mt][kk][0], bl, acc[mt][nt]);
          acc[mt][nt] = MFMA16(a1f[mt][kk][1], bh, acc[mt][nt]);
        }
      }

    const u32 mw0 = bmrow[ci * 64 + wth * 32 + c];
    const u32 mw1 = bmrow[ci * 64 + wth * 32 + 16 + c];
    #pragma unroll
    for (int mt = 0; mt < 2; ++mt)
      #pragma unroll
      for (int nt = 0; nt < 2; ++nt) {
        const u32 mwv = nt ? mw1 : mw0;
        #pragma unroll
        for (int r = 0; r < 4; ++r) {
          float ex = EXP2F(acc[mt][nt][r] * L2E);
          rl[mt][r] += ((mwv >> (mt * 16 + g * 4 + r)) & 1u) ? 0.f : ex;
        }
      }

    __syncthreads();
  }

  // reduce across c lanes, merge t-halves, write invl
  #pragma unroll
  for (int mt = 0; mt < 2; ++mt)
    #pragma unroll
    for (int r = 0; r < 4; ++r) {
      float s = rl[mt][r];
      #pragma unroll
      for (int off = 1; off < 16; off <<= 1) s += __shfl_xor(s, off);
      rl[mt][r] = s;
    }
  __syncthreads();
  if (c == 0) {
    #pragma unroll
    for (int mt = 0; mt < 2; ++mt)
      #pragma unroll
      for (int r = 0; r < 4; ++r)
        mll[w * 32 + mt * 16 + g * 4 + r] = rl[mt][r];
  }
  __syncthreads();
  if (wth == 0 && c == 0) {
    #pragma unroll
    for (int mt = 0; mt < 2; ++mt)
      #pragma unroll
      for (int r = 0; r < 4; ++r) {
        float tot = rl[mt][r] + mll[(w ^ 1) * 32 + mt * 16 + g * 4 + r];
        invl[h * S_LEN + sbase + mt * 16 + g * 4 + r] = 1.0f / tot;
      }
  }
}

// ---- K3 (pass 2): recompute scores (bitwise-identical chain), attn = exp*invl,
//      stage per-wave 32x32 fp32 chunk in LDS, row-store as 128B full lines,
//      PV on normalized attn (bf16) -> out. ----
__launch_bounds__(512, 2)
__global__ void fattn_pass2(const u16* __restrict__ a1hi, const u16* __restrict__ a1lo,
                            const u16* __restrict__ a2hi, const u16* __restrict__ a2lo,
                            const u16* __restrict__ vhi,  const u16* __restrict__ vlo,
                            const u32* __restrict__ bmT,  const float* __restrict__ invl,
                            float* __restrict__ dout) {
  const int h   = blockIdx.x & 7;
  const int sb  = blockIdx.x >> 3;
  const int tid = threadIdx.x;
  const int w = tid >> 6, lane = tid & 63;
  const int g = lane >> 4, c = lane & 15;
  const int wsr = w >> 1;
  const int wth = w & 1;
  const int sbase = sb * 128 + wsr * 32;
  const int sb32  = sb * 4 + wsr;

  __shared__ __align__(16) char smem[103424];
  // dbuf: 2 x 32768 {a2h 8K, a2l 8K, vh 8K, vl 8K}; atbf per-wave [32][36] f32 at 65536
  float* atbf = (float*)(smem + 65536);
  float* mll  = (float*)(smem + 102400);
  (void)mll;

  bf16x8 a1f[2][2][2];
  #pragma unroll
  for (int mt = 0; mt < 2; ++mt)
    #pragma unroll
    for (int kk = 0; kk < 2; ++kk) {
      size_t base = (size_t)(h * S_LEN + sbase + mt * 16 + c) * 64 + kk * 32 + g * 8;
      a1f[mt][kk][0] = *(const bf16x8*)(a1hi + base);
      a1f[mt][kk][1] = *(const bf16x8*)(a1lo + base);
    }

  float inv[2][4];
  #pragma unroll
  for (int mt = 0; mt < 2; ++mt)
    #pragma unroll
    for (int r = 0; r < 4; ++r)
      inv[mt][r] = invl[h * S_LEN + sbase + mt * 16 + g * 4 + r];

  f32x4 oacc[2][4];
  #pragma unroll
  for (int mt = 0; mt < 2; ++mt)
    #pragma unroll
    for (int dt = 0; dt < 4; ++dt) oacc[mt][dt] = (f32x4){0.f, 0.f, 0.f, 0.f};

  const u32* bmrow = bmT + (size_t)sb32 * S_LEN;
  float* aout = dout + (size_t)NHEAD * S_LEN * 64;
  float* myatb = atbf + w * 1152;                    // [32][36] floats

  auto stage_all = [&](int bufi, int ci) {
    const size_t tb = (size_t)(h * 64 + ci) * 4096;
    char* lb = smem + bufi * 32768;
    const int off = w * 1024 + lane * 16;
    gl_lds16((const char*)(a2hi + tb) + off, lb +         w * 1024);
    gl_lds16((const char*)(a2lo + tb) + off, lb +  8192 + w * 1024);
    gl_lds16((const char*)(vhi  + tb) + off, lb + 16384 + w * 1024);
    gl_lds16((const char*)(vlo  + tb) + off, lb + 24576 + w * 1024);
  };

  stage_all(0, 0);
  __syncthreads();

  #pragma unroll 1
  for (int ci = 0; ci < 64; ++ci) {
    if (ci < 63) stage_all((ci + 1) & 1, ci + 1);

    const u16* base = (const u16*)(smem + (ci & 1) * 32768);

    // scores — identical chain to pass 1 (bitwise-equal acc)
    f32x4 acc[2][2];
    #pragma unroll
    for (int mt = 0; mt < 2; ++mt)
      #pragma unroll
      for (int nt = 0; nt < 2; ++nt) acc[mt][nt] = (f32x4){0.f, 0.f, 0.f, 0.f};
    #pragma unroll
    for (int kk = 0; kk < 2; ++kk)
      #pragma unroll
      for (int nt = 0; nt < 2; ++nt) {
        int eb = (wth * 32 + nt * 16 + c) * 64 + ((kk * 32 + g * 8) ^ ((c & 7) << 3));
        bf16x8 bh = *(const bf16x8*)(base + eb);
        bf16x8 bl = *(const bf16x8*)(base + 4096 + eb);
        #pragma unroll
        for (int mt = 0; mt < 2; ++mt) {
          acc[mt][nt] = MFMA16(a1f[mt][kk][0], bh, acc[mt][nt]);
          acc[mt][nt] = MFMA16(a1f[mt][kk][0], bl, acc[mt][nt]);
          acc[mt][nt] = MFMA16(a1f[mt][kk][1], bh, acc[mt][nt]);
        }
      }

    // attn = exp2(score*log2e) * invl (masked -> 0), staged fp32 into per-wave LDS chunk
    const u32 mw0 = bmrow[ci * 64 + wth * 32 + c];
    const u32 mw1 = bmrow[ci * 64 + wth * 32 + 16 + c];
    #pragma unroll
    for (int mt = 0; mt < 2; ++mt)
      #pragma unroll
      for (int nt = 0; nt < 2; ++nt) {
        const u32 mwv = nt ? mw1 : mw0;
        #pragma unroll
        for (int r = 0; r < 4; ++r) {
          float ex = EXP2F(acc[mt][nt][r] * L2E);
          float av = ((mwv >> (mt * 16 + g * 4 + r)) & 1u) ? 0.f : ex * inv[mt][r];
          myatb[(mt * 16 + g * 4 + r) * 36 + nt * 16 + c] = av;
        }
      }

    asm volatile("" ::: "memory");   // keep ds_writes above the cross-lane ds_reads

    // A-fragments for PV from the staged chunk (row = mt*16+c, k = g*8..g*8+7)
    bf16x8 af[2];
    #pragma unroll
    for (int mt = 0; mt < 2; ++mt) {
      const float* arow = myatb + (mt * 16 + c) * 36 + g * 8;
      float4 f0 = *(const float4*)(arow);
      float4 f1 = *(const float4*)(arow + 4);
      af[mt][0] = f2bf(f0.x); af[mt][1] = f2bf(f0.y);
      af[mt][2] = f2bf(f0.z); af[mt][3] = f2bf(f0.w);
      af[mt][4] = f2bf(f1.x); af[mt][5] = f2bf(f1.y);
      af[mt][6] = f2bf(f1.z); af[mt][7] = f2bf(f1.w);
    }

    // full-line attn store: 8 insts, each 4 rows x 128B (lane (g,c): row i*4+g, t 2c..2c+1)
    {
      const size_t rb = (size_t)(h * S_LEN + sbase) * S_LEN + ci * 64 + wth * 32;
      #pragma unroll
      for (int i = 0; i < 8; ++i) {
        float2 vv = *(const float2*)(myatb + (i * 4 + g) * 36 + 2 * c);
        *(float2*)(aout + rb + (size_t)(i * 4 + g) * S_LEN + 2 * c) = vv;
      }
    }

    // PV (normalized attn x v, bf16)
    #pragma unroll
    for (int dt = 0; dt < 4; ++dt) {
      int ve = (dt * 16 + c) * 64 + ((wth * 32 + g * 8) ^ ((c & 7) << 3));
      bf16x8 bvh = *(const bf16x8*)(base + 8192 + ve);
      bf16x8 bvl = *(const bf16x8*)(base + 12288 + ve);
      #pragma unroll
      for (int mt = 0; mt < 2; ++mt) {
        oacc[mt][dt] = MFMA16(af[mt], bvh, oacc[mt][dt]);
        oacc[mt][dt] = MFMA16(af[mt], bvl, oacc[mt][dt]);
      }
    }

    __syncthreads();
  }

  // epilogue: merge t-half partial outputs (already normalized), store out
  __syncthreads();
  float* outx = (float*)smem;            // [4 wsr][32][66] f32 = 33792 B, aliases staging
  if (wth == 1) {
    #pragma unroll
    for (int mt = 0; mt < 2; ++mt)
      #pragma unroll
      for (int dt = 0; dt < 4; ++dt)
        #pragma unroll
        for (int r = 0; r < 4; ++r)
          outx[wsr * 2112 + (mt * 16 + g * 4 + r) * 66 + dt * 16 + c] = oacc[mt][dt][r];
  }
  __syncthreads();
  if (wth == 0) {
    #pragma unroll
    for (int mt = 0; mt < 2; ++mt)
      #pragma unroll
      for (int dt = 0; dt < 4; ++dt)
        #pragma unroll
        for (int r = 0; r < 4; ++r) {
          float vv = oacc[mt][dt][r] + outx[wsr * 2112 + (mt * 16 + g * 4 + r) * 66 + dt * 16 + c];
          int s = sbase + mt * 16 + g * 4 + r;
          dout[(size_t)(h * S_LEN + s) * 64 + dt * 16 + c] = vv;
        }
  }
}

extern "C" void kernel_launch(void* const* d_in, const int* in_sizes, int n_in,
                              void* d_out, int out_size, void* d_ws, size_t ws_size,
                              hipStream_t stream) {
  (void)in_sizes; (void)n_in; (void)out_size; (void)ws_size;
  const float* v    = (const float*)d_in[0];
  const float* A1   = (const float*)d_in[1];
  const float* A2   = (const float*)d_in[2];
  const int*   mask = (const int*)d_in[3];
  float* out = (float*)d_out;
  char* ws = (char*)d_ws;

  u16* a1hi = (u16*)(ws + WS_A1HI);
  u16* a1lo = (u16*)(ws + WS_A1LO);
  u16* a2hi = (u16*)(ws + WS_A2HI);
  u16* a2lo = (u16*)(ws + WS_A2LO);
  u16* vhi  = (u16*)(ws + WS_VHI);
  u16* vlo  = (u16*)(ws + WS_VLO);
  u32* bmT  = (u32*)(ws + WS_BM);
  float* invl = (float*)(ws + WS_INVL);

  pk_mask  <<<2048, 256, 0, stream>>>(mask, bmT);
  pk_split <<<2048, 256, 0, stream>>>(A1, a1hi, a1lo);
  pk_tsplit<<<512,  256, 0, stream>>>(A2, a2hi, a2lo, 64, 4096);   // A2[f][t] -> [t][f]
  pk_tsplit<<<512,  256, 0, stream>>>(v,  vhi,  vlo,  4096, 64);   // v[t][d]  -> [d][t]
  fattn_pass1<<<256, 512, 0, stream>>>(a1hi, a1lo, a2hi, a2lo, bmT, invl);
  fattn_pass2<<<256, 512, 0, stream>>>(a1hi, a1lo, a2hi, a2lo, vhi, vlo, bmT, invl, out);
}

// Round 5
// 768.554 us; speedup vs baseline: 1.0510x; 1.0334x over previous
//
#include <hip/hip_runtime.h>
#include <hip/hip_bf16.h>
#include <stdint.h>

#define S_LEN 4096
#define NHEAD 8
#define L2E   1.44269504088896340736f

typedef __attribute__((ext_vector_type(8))) short bf16x8;
typedef __attribute__((ext_vector_type(4))) float f32x4;
typedef unsigned short u16;
typedef unsigned int   u32;

#define MFMA16(a,b,c) __builtin_amdgcn_mfma_f32_16x16x32_bf16((a),(b),(c),0,0,0)
#define EXP2F(x) __builtin_amdgcn_exp2f((x))

__device__ __forceinline__ void gl_lds16(const void* g, void* l) {
  __builtin_amdgcn_global_load_lds((const __attribute__((address_space(1))) void*)g,
                                   (__attribute__((address_space(3))) void*)l, 16, 0, 0);
}

__device__ __forceinline__ short f2bf(float x) {
  __hip_bfloat16 h = __float2bfloat16(x);
  return *(short*)&h;
}

// ws layout (bytes)
#define WS_A1HI 0u
#define WS_A1LO (4u<<20)
#define WS_A2HI (8u<<20)
#define WS_A2LO (12u<<20)
#define WS_VHI  (16u<<20)
#define WS_VLO  (20u<<20)
#define WS_BM   (24u<<20)
#define WS_INVL (26u<<20)

// ---- PK1: pack mask (1,1,S,S) int32 -> bitmask bmT[s/32][t] (bit = masked) ----
__global__ void pk_mask(const int* __restrict__ mask, u32* __restrict__ bmT) {
  const int sb = blockIdx.x >> 4;
  const int t  = (blockIdx.x & 15) * 256 + threadIdx.x;
  u32 w = 0;
  #pragma unroll
  for (int j = 0; j < 32; ++j)
    w |= (mask[(size_t)(sb * 32 + j) * S_LEN + t] != 0 ? 1u : 0u) << j;
  bmT[sb * S_LEN + t] = w;
}

// ---- PK2: A1 fp32 -> bf16 hi/lo ----
__global__ void pk_split(const float* __restrict__ src, u16* __restrict__ hi, u16* __restrict__ lo) {
  const int i = blockIdx.x * 256 + threadIdx.x;
  float4 x = ((const float4*)src)[i];
  ushort4 hv, lv;
  #pragma unroll
  for (int j = 0; j < 4; ++j) {
    float xv = ((const float*)&x)[j];
    __hip_bfloat16 hb = __float2bfloat16(xv);
    float hf = __bfloat162float(hb);
    __hip_bfloat16 lb = __float2bfloat16(xv - hf);
    ((u16*)&hv)[j] = *(u16*)&hb;
    ((u16*)&lv)[j] = *(u16*)&lb;
  }
  ((ushort4*)hi)[i] = hv;
  ((ushort4*)lo)[i] = lv;
}

// ---- PK3: 64x64 tile transpose + hi/lo split + XOR pre-swizzle ----
__global__ void pk_tsplit(const float* __restrict__ src, u16* __restrict__ hi, u16* __restrict__ lo,
                          int chunk_stride, int row_stride) {
  const int h = blockIdx.x >> 6, ci = blockIdx.x & 63;
  const float* base = src + (size_t)h * (S_LEN * 64) + (size_t)ci * chunk_stride;
  __shared__ float tile[64][65];
  const int jr = threadIdx.x & 63, ir = threadIdx.x >> 6;
  #pragma unroll
  for (int p = 0; p < 16; ++p) {
    int i = p * 4 + ir;
    tile[i][jr] = base[(size_t)i * row_stride + jr];
  }
  __syncthreads();
  const size_t ob = (size_t)(h * 64 + ci) * 4096;
  #pragma unroll
  for (int p = 0; p < 16; ++p) {
    int o = p * 256 + threadIdx.x;
    int r = o >> 6;
    int cc = (o & 63) ^ ((r & 7) << 3);
    float xv = tile[cc][r];
    __hip_bfloat16 hb = __float2bfloat16(xv);
    float hf = __bfloat162float(hb);
    __hip_bfloat16 lb = __float2bfloat16(xv - hf);
    hi[ob + o] = *(u16*)&hb;
    lo[ob + o] = *(u16*)&lb;
  }
}

// ---- K2 (pass 1): scores -> exp2 -> row sums -> invl.
//      256 thr (4 waves: 2s x 2t), 64 s-rows/WG, grid 512 -> 2+ WG/CU. ----
__launch_bounds__(256, 2)
__global__ void fattn_pass1(const u16* __restrict__ a1hi, const u16* __restrict__ a1lo,
                            const u16* __restrict__ a2hi, const u16* __restrict__ a2lo,
                            const u32* __restrict__ bmT,  float* __restrict__ invl) {
  const int h   = blockIdx.x & 7;
  const int sb  = blockIdx.x >> 3;    // 0..63
  const int tid = threadIdx.x;
  const int w = tid >> 6, lane = tid & 63;
  const int g = lane >> 4, c = lane & 15;
  const int wsr = w >> 1;             // s-half (0/1)
  const int wth = w & 1;              // t-half (0/1)
  const int sbase = sb * 64 + wsr * 32;
  const int sb32  = sb * 2 + wsr;

  __shared__ __align__(16) char smem[33280];   // dbuf 2x16K {a2h 8K, a2l 8K} + mll 512B
  float* mll = (float*)(smem + 32768);

  bf16x8 a1f[2][2][2];
  #pragma unroll
  for (int mt = 0; mt < 2; ++mt)
    #pragma unroll
    for (int kk = 0; kk < 2; ++kk) {
      size_t base = (size_t)(h * S_LEN + sbase + mt * 16 + c) * 64 + kk * 32 + g * 8;
      a1f[mt][kk][0] = *(const bf16x8*)(a1hi + base);
      a1f[mt][kk][1] = *(const bf16x8*)(a1lo + base);
    }

  float rl[2][4];
  #pragma unroll
  for (int mt = 0; mt < 2; ++mt)
    #pragma unroll
    for (int r = 0; r < 4; ++r) rl[mt][r] = 0.f;

  const u32* bmrow = bmT + (size_t)sb32 * S_LEN;

  auto stage2 = [&](int bufi, int ci) {
    const size_t tb = (size_t)(h * 64 + ci) * 4096;
    char* lb = smem + bufi * 16384;
    #pragma unroll
    for (int i = 0; i < 2; ++i) {
      const int off = w * 2048 + i * 1024 + lane * 16;
      gl_lds16((const char*)(a2hi + tb) + off, lb +        off);
      gl_lds16((const char*)(a2lo + tb) + off, lb + 8192 + off);
    }
  };

  stage2(0, 0);
  __syncthreads();

  #pragma unroll 1
  for (int ci = 0; ci < 64; ++ci) {
    if (ci < 63) stage2((ci + 1) & 1, ci + 1);

    const u16* base = (const u16*)(smem + (ci & 1) * 16384);

    f32x4 acc[2][2];
    #pragma unroll
    for (int mt = 0; mt < 2; ++mt)
      #pragma unroll
      for (int nt = 0; nt < 2; ++nt) acc[mt][nt] = (f32x4){0.f, 0.f, 0.f, 0.f};
    #pragma unroll
    for (int kk = 0; kk < 2; ++kk)
      #pragma unroll
      for (int nt = 0; nt < 2; ++nt) {
        int eb = (wth * 32 + nt * 16 + c) * 64 + ((kk * 32 + g * 8) ^ ((c & 7) << 3));
        bf16x8 bh = *(const bf16x8*)(base + eb);
        bf16x8 bl = *(const bf16x8*)(base + 4096 + eb);
        #pragma unroll
        for (int mt = 0; mt < 2; ++mt) {
          acc[mt][nt] = MFMA16(a1f[mt][kk][0], bh, acc[mt][nt]);
          acc[mt][nt] = MFMA16(a1f[mt][kk][0], bl, acc[mt][nt]);
          acc[mt][nt] = MFMA16(a1f[mt][kk][1], bh, acc[mt][nt]);
        }
      }

    const u32 mw0 = bmrow[ci * 64 + wth * 32 + c];
    const u32 mw1 = bmrow[ci * 64 + wth * 32 + 16 + c];
    #pragma unroll
    for (int mt = 0; mt < 2; ++mt)
      #pragma unroll
      for (int nt = 0; nt < 2; ++nt) {
        const u32 mwv = nt ? mw1 : mw0;
        #pragma unroll
        for (int r = 0; r < 4; ++r) {
          float ex = EXP2F(acc[mt][nt][r] * L2E);
          rl[mt][r] += ((mwv >> (mt * 16 + g * 4 + r)) & 1u) ? 0.f : ex;
        }
      }

    __syncthreads();
  }

  #pragma unroll
  for (int mt = 0; mt < 2; ++mt)
    #pragma unroll
    for (int r = 0; r < 4; ++r) {
      float s = rl[mt][r];
      #pragma unroll
      for (int off = 1; off < 16; off <<= 1) s += __shfl_xor(s, off);
      rl[mt][r] = s;
    }
  __syncthreads();
  if (c == 0) {
    #pragma unroll
    for (int mt = 0; mt < 2; ++mt)
      #pragma unroll
      for (int r = 0; r < 4; ++r)
        mll[w * 32 + mt * 16 + g * 4 + r] = rl[mt][r];
  }
  __syncthreads();
  if (wth == 0 && c == 0) {
    #pragma unroll
    for (int mt = 0; mt < 2; ++mt)
      #pragma unroll
      for (int r = 0; r < 4; ++r) {
        float tot = rl[mt][r] + mll[(w ^ 1) * 32 + mt * 16 + g * 4 + r];
        invl[h * S_LEN + sbase + mt * 16 + g * 4 + r] = 1.0f / tot;
      }
  }
}

// ---- K3 (pass 2): recompute scores, attn = exp*invl (direct reg stores),
//      PV via per-wave LDS transpose -> out. 256 thr, 64 rows/WG, grid 512,
//      LDS 74 KB -> 2 WG/CU (barrier-decoupled overlap). ----
__launch_bounds__(256, 2)
__global__ void fattn_pass2(const u16* __restrict__ a1hi, const u16* __restrict__ a1lo,
                            const u16* __restrict__ a2hi, const u16* __restrict__ a2lo,
                            const u16* __restrict__ vhi,  const u16* __restrict__ vlo,
                            const u32* __restrict__ bmT,  const float* __restrict__ invl,
                            float* __restrict__ dout) {
  const int h   = blockIdx.x & 7;
  const int sb  = blockIdx.x >> 3;
  const int tid = threadIdx.x;
  const int w = tid >> 6, lane = tid & 63;
  const int g = lane >> 4, c = lane & 15;
  const int wsr = w >> 1;
  const int wth = w & 1;
  const int sbase = sb * 64 + wsr * 32;
  const int sb32  = sb * 2 + wsr;

  __shared__ __align__(16) char smem[75776];
  // dbuf: 2 x 32768 {a2h 8K, a2l 8K, vh 8K, vl 8K}; atb per-wave [32][40] bf16 at 65536
  u16* atb = (u16*)(smem + 65536);     // 4 waves x 2560 B = 10240 B

  bf16x8 a1f[2][2][2];
  #pragma unroll
  for (int mt = 0; mt < 2; ++mt)
    #pragma unroll
    for (int kk = 0; kk < 2; ++kk) {
      size_t base = (size_t)(h * S_LEN + sbase + mt * 16 + c) * 64 + kk * 32 + g * 8;
      a1f[mt][kk][0] = *(const bf16x8*)(a1hi + base);
      a1f[mt][kk][1] = *(const bf16x8*)(a1lo + base);
    }

  float inv[2][4];
  #pragma unroll
  for (int mt = 0; mt < 2; ++mt)
    #pragma unroll
    for (int r = 0; r < 4; ++r)
      inv[mt][r] = invl[h * S_LEN + sbase + mt * 16 + g * 4 + r];

  f32x4 oacc[2][4];
  #pragma unroll
  for (int mt = 0; mt < 2; ++mt)
    #pragma unroll
    for (int dt = 0; dt < 4; ++dt) oacc[mt][dt] = (f32x4){0.f, 0.f, 0.f, 0.f};

  const u32* bmrow = bmT + (size_t)sb32 * S_LEN;
  float* aout = dout + (size_t)NHEAD * S_LEN * 64;
  u16* myatb = atb + w * 1280;

  auto stage_all = [&](int bufi, int ci) {
    const size_t tb = (size_t)(h * 64 + ci) * 4096;
    char* lb = smem + bufi * 32768;
    #pragma unroll
    for (int i = 0; i < 2; ++i) {
      const int off = w * 2048 + i * 1024 + lane * 16;
      gl_lds16((const char*)(a2hi + tb) + off, lb +         off);
      gl_lds16((const char*)(a2lo + tb) + off, lb +  8192 + off);
      gl_lds16((const char*)(vhi  + tb) + off, lb + 16384 + off);
      gl_lds16((const char*)(vlo  + tb) + off, lb + 24576 + off);
    }
  };

  stage_all(0, 0);
  __syncthreads();

  #pragma unroll 1
  for (int ci = 0; ci < 64; ++ci) {
    if (ci < 63) stage_all((ci + 1) & 1, ci + 1);

    const u16* base = (const u16*)(smem + (ci & 1) * 32768);

    // scores
    f32x4 acc[2][2];
    #pragma unroll
    for (int mt = 0; mt < 2; ++mt)
      #pragma unroll
      for (int nt = 0; nt < 2; ++nt) acc[mt][nt] = (f32x4){0.f, 0.f, 0.f, 0.f};
    #pragma unroll
    for (int kk = 0; kk < 2; ++kk)
      #pragma unroll
      for (int nt = 0; nt < 2; ++nt) {
        int eb = (wth * 32 + nt * 16 + c) * 64 + ((kk * 32 + g * 8) ^ ((c & 7) << 3));
        bf16x8 bh = *(const bf16x8*)(base + eb);
        bf16x8 bl = *(const bf16x8*)(base + 4096 + eb);
        #pragma unroll
        for (int mt = 0; mt < 2; ++mt) {
          acc[mt][nt] = MFMA16(a1f[mt][kk][0], bh, acc[mt][nt]);
          acc[mt][nt] = MFMA16(a1f[mt][kk][0], bl, acc[mt][nt]);
          acc[mt][nt] = MFMA16(a1f[mt][kk][1], bh, acc[mt][nt]);
        }
      }

    // attn = exp * invl (masked -> 0), in regs
    const u32 mw0 = bmrow[ci * 64 + wth * 32 + c];
    const u32 mw1 = bmrow[ci * 64 + wth * 32 + 16 + c];
    float av[2][2][4];
    #pragma unroll
    for (int mt = 0; mt < 2; ++mt)
      #pragma unroll
      for (int nt = 0; nt < 2; ++nt) {
        const u32 mwv = nt ? mw1 : mw0;
        #pragma unroll
        for (int r = 0; r < 4; ++r) {
          float ex = EXP2F(acc[mt][nt][r] * L2E);
          av[mt][nt][r] = ((mwv >> (mt * 16 + g * 4 + r)) & 1u) ? 0.f : ex * inv[mt][r];
        }
      }

    // transpose attn (bf16) via per-wave LDS buf for the PV A-fragment
    #pragma unroll
    for (int mt = 0; mt < 2; ++mt)
      #pragma unroll
      for (int nt = 0; nt < 2; ++nt)
        #pragma unroll
        for (int r = 0; r < 4; ++r)
          myatb[(mt * 16 + g * 4 + r) * 40 + nt * 16 + c] = (u16)f2bf(av[mt][nt][r]);

    asm volatile("" ::: "memory");

    bf16x8 af[2];
    #pragma unroll
    for (int mt = 0; mt < 2; ++mt)
      af[mt] = *(const bf16x8*)(myatb + (mt * 16 + c) * 40 + g * 8);

    // attn store straight from regs (64B segments per (mt,nt,r) across c-lanes)
    {
      const size_t rb = (size_t)(h * S_LEN + sbase) * S_LEN + ci * 64 + wth * 32;
      #pragma unroll
      for (int mt = 0; mt < 2; ++mt)
        #pragma unroll
        for (int nt = 0; nt < 2; ++nt)
          #pragma unroll
          for (int r = 0; r < 4; ++r)
            aout[rb + (size_t)(mt * 16 + g * 4 + r) * S_LEN + nt * 16 + c] = av[mt][nt][r];
    }

    // PV (normalized attn x v)
    #pragma unroll
    for (int dt = 0; dt < 4; ++dt) {
      int ve = (dt * 16 + c) * 64 + ((wth * 32 + g * 8) ^ ((c & 7) << 3));
      bf16x8 bvh = *(const bf16x8*)(base + 8192 + ve);
      bf16x8 bvl = *(const bf16x8*)(base + 12288 + ve);
      #pragma unroll
      for (int mt = 0; mt < 2; ++mt) {
        oacc[mt][dt] = MFMA16(af[mt], bvh, oacc[mt][dt]);
        oacc[mt][dt] = MFMA16(af[mt], bvl, oacc[mt][dt]);
      }
    }

    __syncthreads();
  }

  // epilogue: merge t-half partial outputs, store out
  __syncthreads();
  float* outx = (float*)smem;            // [2 wsr][32][66] f32 = 16896 B, aliases staging
  if (wth == 1) {
    #pragma unroll
    for (int mt = 0; mt < 2; ++mt)
      #pragma unroll
      for (int dt = 0; dt < 4; ++dt)
        #pragma unroll
        for (int r = 0; r < 4; ++r)
          outx[wsr * 2112 + (mt * 16 + g * 4 + r) * 66 + dt * 16 + c] = oacc[mt][dt][r];
  }
  __syncthreads();
  if (wth == 0) {
    #pragma unroll
    for (int mt = 0; mt < 2; ++mt)
      #pragma unroll
      for (int dt = 0; dt < 4; ++dt)
        #pragma unroll
        for (int r = 0; r < 4; ++r) {
          float vv = oacc[mt][dt][r] + outx[wsr * 2112 + (mt * 16 + g * 4 + r) * 66 + dt * 16 + c];
          int s = sbase + mt * 16 + g * 4 + r;
          dout[(size_t)(h * S_LEN + s) * 64 + dt * 16 + c] = vv;
        }
  }
}

extern "C" void kernel_launch(void* const* d_in, const int* in_sizes, int n_in,
                              void* d_out, int out_size, void* d_ws, size_t ws_size,
                              hipStream_t stream) {
  (void)in_sizes; (void)n_in; (void)out_size; (void)ws_size;
  const float* v    = (const float*)d_in[0];
  const float* A1   = (const float*)d_in[1];
  const float* A2   = (const float*)d_in[2];
  const int*   mask = (const int*)d_in[3];
  float* out = (float*)d_out;
  char* ws = (char*)d_ws;

  u16* a1hi = (u16*)(ws + WS_A1HI);
  u16* a1lo = (u16*)(ws + WS_A1LO);
  u16* a2hi = (u16*)(ws + WS_A2HI);
  u16* a2lo = (u16*)(ws + WS_A2LO);
  u16* vhi  = (u16*)(ws + WS_VHI);
  u16* vlo  = (u16*)(ws + WS_VLO);
  u32* bmT  = (u32*)(ws + WS_BM);
  float* invl = (float*)(ws + WS_INVL);

  pk_mask  <<<2048, 256, 0, stream>>>(mask, bmT);
  pk_split <<<2048, 256, 0, stream>>>(A1, a1hi, a1lo);
  pk_tsplit<<<512,  256, 0, stream>>>(A2, a2hi, a2lo, 64, 4096);   // A2[f][t] -> [t][f]
  pk_tsplit<<<512,  256, 0, stream>>>(v,  vhi,  vlo,  4096, 64);   // v[t][d]  -> [d][t]
  fattn_pass1<<<512, 256, 0, stream>>>(a1hi, a1lo, a2hi, a2lo, bmT, invl);
  fattn_pass2<<<512, 256, 0, stream>>>(a1hi, a1lo, a2hi, a2lo, vhi, vlo, bmT, invl, out);
}

// Round 6
// 730.439 us; speedup vs baseline: 1.1059x; 1.0522x over previous
//
#include <hip/hip_runtime.h>
#include <hip/hip_bf16.h>
#include <stdint.h>

#define S_LEN 4096
#define NHEAD 8
#define L2E   1.44269504088896340736f

typedef __attribute__((ext_vector_type(8))) _Float16 f16x8;
typedef __attribute__((ext_vector_type(4))) float f32x4;
typedef unsigned short u16;
typedef unsigned int   u32;

#define MFMA16F(a,b,c) __builtin_amdgcn_mfma_f32_16x16x32_f16((a),(b),(c),0,0,0)
#define EXP2F(x) __builtin_amdgcn_exp2f((x))

__device__ __forceinline__ void gl_lds16(const void* g, void* l) {
  __builtin_amdgcn_global_load_lds((const __attribute__((address_space(1))) void*)g,
                                   (__attribute__((address_space(3))) void*)l, 16, 0, 0);
}

// ws layout (bytes)
#define WS_A2F  0u
#define WS_VF   (4u<<20)
#define WS_BM   (8u<<20)
#define WS_INVL (10u<<20)

// ---- PK1: pack mask (1,1,S,S) int32 -> bitmask bmT[s/32][t] (bit = masked) ----
__global__ void pk_mask(const int* __restrict__ mask, u32* __restrict__ bmT) {
  const int sb = blockIdx.x >> 4;
  const int t  = (blockIdx.x & 15) * 256 + threadIdx.x;
  u32 w = 0;
  #pragma unroll
  for (int j = 0; j < 32; ++j)
    w |= (mask[(size_t)(sb * 32 + j) * S_LEN + t] != 0 ? 1u : 0u) << j;
  bmT[sb * S_LEN + t] = w;
}

// ---- PK2: 64x64 tile transpose + f16 convert + XOR pre-swizzle ----
// element (r,c) of transposed tile lives at o = r*64 + (c ^ ((r&7)<<3))
__global__ void pk_tsplit16(const float* __restrict__ src, _Float16* __restrict__ dst,
                            int chunk_stride, int row_stride) {
  const int h = blockIdx.x >> 6, ci = blockIdx.x & 63;
  const float* base = src + (size_t)h * (S_LEN * 64) + (size_t)ci * chunk_stride;
  __shared__ float tile[64][65];
  const int jr = threadIdx.x & 63, ir = threadIdx.x >> 6;
  #pragma unroll
  for (int p = 0; p < 16; ++p) {
    int i = p * 4 + ir;
    tile[i][jr] = base[(size_t)i * row_stride + jr];
  }
  __syncthreads();
  const size_t ob = (size_t)(h * 64 + ci) * 4096;
  #pragma unroll
  for (int p = 0; p < 16; ++p) {
    int o = p * 256 + threadIdx.x;
    int r = o >> 6;
    int cc = (o & 63) ^ ((r & 7) << 3);
    dst[ob + o] = (_Float16)tile[cc][r];
  }
}

// shared helper: load A1 fragments (fp32 global -> f16 regs), identical in both passes
__device__ __forceinline__ void load_a1(const float* __restrict__ A1, int h, int sbase,
                                        int c, int g, f16x8 (&a1f)[2][2]) {
  #pragma unroll
  for (int mt = 0; mt < 2; ++mt)
    #pragma unroll
    for (int kk = 0; kk < 2; ++kk) {
      const float* p = A1 + ((size_t)(h * S_LEN + sbase + mt * 16 + c) * 64 + kk * 32 + g * 8);
      float4 x0 = ((const float4*)p)[0];
      float4 x1 = ((const float4*)p)[1];
      f16x8 f;
      f[0] = (_Float16)x0.x; f[1] = (_Float16)x0.y; f[2] = (_Float16)x0.z; f[3] = (_Float16)x0.w;
      f[4] = (_Float16)x1.x; f[5] = (_Float16)x1.y; f[6] = (_Float16)x1.z; f[7] = (_Float16)x1.w;
      a1f[mt][kk] = f;
    }
}

// ---- K2 (pass 1): f16 scores -> exp2 -> row sums -> invl.
//      256 thr (4 waves: 2s x 2t), 64 s-rows/WG, grid 512. ----
__launch_bounds__(256, 2)
__global__ void fattn_pass1(const float* __restrict__ A1, const _Float16* __restrict__ a2f,
                            const u32* __restrict__ bmT,  float* __restrict__ invl) {
  const int h   = blockIdx.x & 7;
  const int sb  = blockIdx.x >> 3;    // 0..63
  const int tid = threadIdx.x;
  const int w = tid >> 6, lane = tid & 63;
  const int g = lane >> 4, c = lane & 15;
  const int wsr = w >> 1;             // s-half
  const int wth = w & 1;              // t-half
  const int sbase = sb * 64 + wsr * 32;
  const int sb32  = sb * 2 + wsr;

  __shared__ __align__(16) char smem[16896];   // dbuf 2x8K a2f + mll 512B
  float* mll = (float*)(smem + 16384);

  f16x8 a1f[2][2];
  load_a1(A1, h, sbase, c, g, a1f);

  float rl[2][4];
  #pragma unroll
  for (int mt = 0; mt < 2; ++mt)
    #pragma unroll
    for (int r = 0; r < 4; ++r) rl[mt][r] = 0.f;

  const u32* bmrow = bmT + (size_t)sb32 * S_LEN;

  auto stage2 = [&](int bufi, int ci) {
    const size_t tb = (size_t)(h * 64 + ci) * 4096;   // elements
    char* lb = smem + bufi * 8192;
    #pragma unroll
    for (int i = 0; i < 2; ++i) {
      const int off = i * 4096 + tid * 16;
      gl_lds16((const char*)(a2f + tb) + off, lb + off);
    }
  };

  stage2(0, 0);
  __syncthreads();

  #pragma unroll 1
  for (int ci = 0; ci < 64; ++ci) {
    if (ci < 63) stage2((ci + 1) & 1, ci + 1);

    const _Float16* base = (const _Float16*)(smem + (ci & 1) * 8192);

    f32x4 acc[2][2];
    #pragma unroll
    for (int mt = 0; mt < 2; ++mt)
      #pragma unroll
      for (int nt = 0; nt < 2; ++nt) acc[mt][nt] = (f32x4){0.f, 0.f, 0.f, 0.f};
    #pragma unroll
    for (int kk = 0; kk < 2; ++kk)
      #pragma unroll
      for (int nt = 0; nt < 2; ++nt) {
        int eb = (wth * 32 + nt * 16 + c) * 64 + ((kk * 32 + g * 8) ^ ((c & 7) << 3));
        f16x8 bh = *(const f16x8*)(base + eb);
        #pragma unroll
        for (int mt = 0; mt < 2; ++mt)
          acc[mt][nt] = MFMA16F(a1f[mt][kk], bh, acc[mt][nt]);
      }

    const u32 mw0 = bmrow[ci * 64 + wth * 32 + c];
    const u32 mw1 = bmrow[ci * 64 + wth * 32 + 16 + c];
    #pragma unroll
    for (int mt = 0; mt < 2; ++mt)
      #pragma unroll
      for (int nt = 0; nt < 2; ++nt) {
        const u32 mwv = nt ? mw1 : mw0;
        #pragma unroll
        for (int r = 0; r < 4; ++r) {
          float ex = EXP2F(acc[mt][nt][r] * L2E);
          rl[mt][r] += ((mwv >> (mt * 16 + g * 4 + r)) & 1u) ? 0.f : ex;
        }
      }

    __syncthreads();
  }

  #pragma unroll
  for (int mt = 0; mt < 2; ++mt)
    #pragma unroll
    for (int r = 0; r < 4; ++r) {
      float s = rl[mt][r];
      #pragma unroll
      for (int off = 1; off < 16; off <<= 1) s += __shfl_xor(s, off);
      rl[mt][r] = s;
    }
  __syncthreads();
  if (c == 0) {
    #pragma unroll
    for (int mt = 0; mt < 2; ++mt)
      #pragma unroll
      for (int r = 0; r < 4; ++r)
        mll[w * 32 + mt * 16 + g * 4 + r] = rl[mt][r];
  }
  __syncthreads();
  if (wth == 0 && c == 0) {
    #pragma unroll
    for (int mt = 0; mt < 2; ++mt)
      #pragma unroll
      for (int r = 0; r < 4; ++r) {
        float tot = rl[mt][r] + mll[(w ^ 1) * 32 + mt * 16 + g * 4 + r];
        invl[h * S_LEN + sbase + mt * 16 + g * 4 + r] = 1.0f / tot;
      }
  }
}

// ---- K3 (pass 2): recompute f16 scores (identical chain), attn = exp*invl,
//      reg stores for attn, PV (f16 attn x f16 v) -> out. LDS 42 KB. ----
__launch_bounds__(256, 2)
__global__ void fattn_pass2(const float* __restrict__ A1, const _Float16* __restrict__ a2f,
                            const _Float16* __restrict__ vf, const u32* __restrict__ bmT,
                            const float* __restrict__ invl, float* __restrict__ dout) {
  const int h   = blockIdx.x & 7;
  const int sb  = blockIdx.x >> 3;
  const int tid = threadIdx.x;
  const int w = tid >> 6, lane = tid & 63;
  const int g = lane >> 4, c = lane & 15;
  const int wsr = w >> 1;
  const int wth = w & 1;
  const int sbase = sb * 64 + wsr * 32;
  const int sb32  = sb * 2 + wsr;

  __shared__ __align__(16) char smem[43008];
  // dbuf: 2 x 16384 {a2f 8K, vf 8K}; atb per-wave [32][40] f16 at 32768 (4x2560B)
  _Float16* atb = (_Float16*)(smem + 32768);

  f16x8 a1f[2][2];
  load_a1(A1, h, sbase, c, g, a1f);

  float inv[2][4];
  #pragma unroll
  for (int mt = 0; mt < 2; ++mt)
    #pragma unroll
    for (int r = 0; r < 4; ++r)
      inv[mt][r] = invl[h * S_LEN + sbase + mt * 16 + g * 4 + r];

  f32x4 oacc[2][4];
  #pragma unroll
  for (int mt = 0; mt < 2; ++mt)
    #pragma unroll
    for (int dt = 0; dt < 4; ++dt) oacc[mt][dt] = (f32x4){0.f, 0.f, 0.f, 0.f};

  const u32* bmrow = bmT + (size_t)sb32 * S_LEN;
  float* aout = dout + (size_t)NHEAD * S_LEN * 64;
  _Float16* myatb = atb + w * 1280;

  auto stage_all = [&](int bufi, int ci) {
    const size_t tb = (size_t)(h * 64 + ci) * 4096;
    char* lb = smem + bufi * 16384;
    #pragma unroll
    for (int i = 0; i < 2; ++i) {
      const int off = i * 4096 + tid * 16;
      gl_lds16((const char*)(a2f + tb) + off, lb +        off);
      gl_lds16((const char*)(vf  + tb) + off, lb + 8192 + off);
    }
  };

  stage_all(0, 0);
  __syncthreads();

  #pragma unroll 1
  for (int ci = 0; ci < 64; ++ci) {
    if (ci < 63) stage_all((ci + 1) & 1, ci + 1);

    const _Float16* base = (const _Float16*)(smem + (ci & 1) * 16384);

    // scores — identical chain to pass 1
    f32x4 acc[2][2];
    #pragma unroll
    for (int mt = 0; mt < 2; ++mt)
      #pragma unroll
      for (int nt = 0; nt < 2; ++nt) acc[mt][nt] = (f32x4){0.f, 0.f, 0.f, 0.f};
    #pragma unroll
    for (int kk = 0; kk < 2; ++kk)
      #pragma unroll
      for (int nt = 0; nt < 2; ++nt) {
        int eb = (wth * 32 + nt * 16 + c) * 64 + ((kk * 32 + g * 8) ^ ((c & 7) << 3));
        f16x8 bh = *(const f16x8*)(base + eb);
        #pragma unroll
        for (int mt = 0; mt < 2; ++mt)
          acc[mt][nt] = MFMA16F(a1f[mt][kk], bh, acc[mt][nt]);
      }

    // attn = exp2 * invl (masked -> 0)
    const u32 mw0 = bmrow[ci * 64 + wth * 32 + c];
    const u32 mw1 = bmrow[ci * 64 + wth * 32 + 16 + c];
    float av[2][2][4];
    #pragma unroll
    for (int mt = 0; mt < 2; ++mt)
      #pragma unroll
      for (int nt = 0; nt < 2; ++nt) {
        const u32 mwv = nt ? mw1 : mw0;
        #pragma unroll
        for (int r = 0; r < 4; ++r) {
          float ex = EXP2F(acc[mt][nt][r] * L2E);
          av[mt][nt][r] = ((mwv >> (mt * 16 + g * 4 + r)) & 1u) ? 0.f : ex * inv[mt][r];
        }
      }

    // transpose attn (f16) via per-wave LDS buf for the PV A-fragment
    #pragma unroll
    for (int mt = 0; mt < 2; ++mt)
      #pragma unroll
      for (int nt = 0; nt < 2; ++nt)
        #pragma unroll
        for (int r = 0; r < 4; ++r)
          myatb[(mt * 16 + g * 4 + r) * 40 + nt * 16 + c] = (_Float16)av[mt][nt][r];

    asm volatile("" ::: "memory");

    f16x8 af[2];
    #pragma unroll
    for (int mt = 0; mt < 2; ++mt)
      af[mt] = *(const f16x8*)(myatb + (mt * 16 + c) * 40 + g * 8);

    // attn store straight from regs (fp32; 64B segments merge to full lines in L2)
    {
      const size_t rb = (size_t)(h * S_LEN + sbase) * S_LEN + ci * 64 + wth * 32;
      #pragma unroll
      for (int mt = 0; mt < 2; ++mt)
        #pragma unroll
        for (int nt = 0; nt < 2; ++nt)
          #pragma unroll
          for (int r = 0; r < 4; ++r)
            aout[rb + (size_t)(mt * 16 + g * 4 + r) * S_LEN + nt * 16 + c] = av[mt][nt][r];
    }

    // PV (normalized f16 attn x f16 v)
    #pragma unroll
    for (int dt = 0; dt < 4; ++dt) {
      int ve = (dt * 16 + c) * 64 + ((wth * 32 + g * 8) ^ ((c & 7) << 3));
      f16x8 bv = *(const f16x8*)(base + 4096 + ve);
      #pragma unroll
      for (int mt = 0; mt < 2; ++mt)
        oacc[mt][dt] = MFMA16F(af[mt], bv, oacc[mt][dt]);
    }

    __syncthreads();
  }

  // epilogue: merge t-half partial outputs, store out
  __syncthreads();
  float* outx = (float*)smem;            // [2 wsr][32][66] f32 = 16896 B
  if (wth == 1) {
    #pragma unroll
    for (int mt = 0; mt < 2; ++mt)
      #pragma unroll
      for (int dt = 0; dt < 4; ++dt)
        #pragma unroll
        for (int r = 0; r < 4; ++r)
          outx[wsr * 2112 + (mt * 16 + g * 4 + r) * 66 + dt * 16 + c] = oacc[mt][dt][r];
  }
  __syncthreads();
  if (wth == 0) {
    #pragma unroll
    for (int mt = 0; mt < 2; ++mt)
      #pragma unroll
      for (int dt = 0; dt < 4; ++dt)
        #pragma unroll
        for (int r = 0; r < 4; ++r) {
          float vv = oacc[mt][dt][r] + outx[wsr * 2112 + (mt * 16 + g * 4 + r) * 66 + dt * 16 + c];
          int s = sbase + mt * 16 + g * 4 + r;
          dout[(size_t)(h * S_LEN + s) * 64 + dt * 16 + c] = vv;
        }
  }
}

extern "C" void kernel_launch(void* const* d_in, const int* in_sizes, int n_in,
                              void* d_out, int out_size, void* d_ws, size_t ws_size,
                              hipStream_t stream) {
  (void)in_sizes; (void)n_in; (void)out_size; (void)ws_size;
  const float* v    = (const float*)d_in[0];
  const float* A1   = (const float*)d_in[1];
  const float* A2   = (const float*)d_in[2];
  const int*   mask = (const int*)d_in[3];
  float* out = (float*)d_out;
  char* ws = (char*)d_ws;

  _Float16* a2f = (_Float16*)(ws + WS_A2F);
  _Float16* vf  = (_Float16*)(ws + WS_VF);
  u32* bmT      = (u32*)(ws + WS_BM);
  float* invl   = (float*)(ws + WS_INVL);

  pk_mask    <<<2048, 256, 0, stream>>>(mask, bmT);
  pk_tsplit16<<<512,  256, 0, stream>>>(A2, a2f, 64, 4096);   // A2[f][t] -> [t][f]
  pk_tsplit16<<<512,  256, 0, stream>>>(v,  vf,  4096, 64);   // v[t][d]  -> [d][t]
  fattn_pass1<<<512, 256, 0, stream>>>(A1, a2f, bmT, invl);
  fattn_pass2<<<512, 256, 0, stream>>>(A1, a2f, vf, bmT, invl, out);
}

// Round 8
// 699.034 us; speedup vs baseline: 1.1555x; 1.0449x over previous
//
#include <hip/hip_runtime.h>
#include <hip/hip_bf16.h>
#include <stdint.h>

#define S_LEN 4096
#define NHEAD 8
#define L2E   1.44269504088896340736f

typedef __attribute__((ext_vector_type(8))) _Float16 f16x8;
typedef __attribute__((ext_vector_type(4))) float f32x4;
typedef unsigned short u16;
typedef unsigned int   u32;

#define MFMA16F(a,b,c) __builtin_amdgcn_mfma_f32_16x16x32_f16((a),(b),(c),0,0,0)
#define EXP2F(x) __builtin_amdgcn_exp2f((x))

__device__ __forceinline__ void gl_lds16(const void* g, void* l) {
  __builtin_amdgcn_global_load_lds((const __attribute__((address_space(1))) void*)g,
                                   (__attribute__((address_space(3))) void*)l, 16, 0, 0);
}

// ws layout (bytes)
#define WS_A2F  0u
#define WS_VF   (4u<<20)
#define WS_BM   (8u<<20)

// ---- PK1: pack mask (1,1,S,S) int32 -> bitmask bmT[s/32][t] (bit = masked) ----
__global__ void pk_mask(const int* __restrict__ mask, u32* __restrict__ bmT) {
  const int sb = blockIdx.x >> 4;
  const int t  = (blockIdx.x & 15) * 256 + threadIdx.x;
  u32 w = 0;
  #pragma unroll
  for (int j = 0; j < 32; ++j)
    w |= (mask[(size_t)(sb * 32 + j) * S_LEN + t] != 0 ? 1u : 0u) << j;
  bmT[sb * S_LEN + t] = w;
}

// ---- PK2: 64x64 tile transpose + f16 convert + XOR pre-swizzle ----
// element (r,c) of transposed tile lives at o = r*64 + (c ^ ((r&7)<<3))
__global__ void pk_tsplit16(const float* __restrict__ src, _Float16* __restrict__ dst,
                            int chunk_stride, int row_stride) {
  const int h = blockIdx.x >> 6, ci = blockIdx.x & 63;
  const float* base = src + (size_t)h * (S_LEN * 64) + (size_t)ci * chunk_stride;
  __shared__ float tile[64][65];
  const int jr = threadIdx.x & 63, ir = threadIdx.x >> 6;
  #pragma unroll
  for (int p = 0; p < 16; ++p) {
    int i = p * 4 + ir;
    tile[i][jr] = base[(size_t)i * row_stride + jr];
  }
  __syncthreads();
  const size_t ob = (size_t)(h * 64 + ci) * 4096;
  #pragma unroll
  for (int p = 0; p < 16; ++p) {
    int o = p * 256 + threadIdx.x;
    int r = o >> 6;
    int cc = (o & 63) ^ ((r & 7) << 3);
    dst[ob + o] = (_Float16)tile[cc][r];
  }
}

// ---- fused kernel: 32 s-rows/WG, grid 1024 (4 WG/CU, 16 waves/CU).
//      Loop1: f16 scores -> exp2 -> row sums (in regs). Cross-wave merge in LDS.
//      Loop2: recompute identical scores, attn = exp*inv, write attn, PV -> out. ----
__launch_bounds__(256, 4)
__global__ void fattn_fused(const float* __restrict__ A1, const _Float16* __restrict__ a2f,
                            const _Float16* __restrict__ vf, const u32* __restrict__ bmT,
                            float* __restrict__ dout) {
  const int h   = blockIdx.x & 7;       // head; blockIdx%8 round-robins XCDs
  const int sb  = blockIdx.x >> 3;      // 0..127 (32-row block)
  const int tid = threadIdx.x;
  const int w = tid >> 6, lane = tid & 63;
  const int g = lane >> 4, c = lane & 15;
  const int wsr = w >> 1;               // s-half (16 rows each)
  const int wth = w & 1;                // t-half (32 t each)
  const int sbase = sb * 32 + wsr * 16;

  __shared__ __align__(16) char smem[38400];
  // dbuf: smem + bufi*16384 : {a2 8K, v 8K}; atb 4x1280B at 32768; mll 256B at 37888
  _Float16* atb = (_Float16*)(smem + 32768);
  float*    mll = (float*)(smem + 37888);

  // A1 fragment (16 rows: row=c, k=kk*32+g*8), fp32 -> f16, shared by both loops
  f16x8 a1f[2];
  #pragma unroll
  for (int kk = 0; kk < 2; ++kk) {
    const float* p = A1 + ((size_t)(h * S_LEN + sbase + c) * 64 + kk * 32 + g * 8);
    float4 x0 = ((const float4*)p)[0];
    float4 x1 = ((const float4*)p)[1];
    f16x8 f;
    f[0] = (_Float16)x0.x; f[1] = (_Float16)x0.y; f[2] = (_Float16)x0.z; f[3] = (_Float16)x0.w;
    f[4] = (_Float16)x1.x; f[5] = (_Float16)x1.y; f[6] = (_Float16)x1.z; f[7] = (_Float16)x1.w;
    a1f[kk] = f;
  }

  const u32* bmrow = bmT + (size_t)sb * S_LEN;
  const int mbit = wsr * 16;            // this wave's rows sit in bits [mbit+g*4+r]

  auto stage_a2 = [&](int bufi, int ci) {
    const size_t tb = (size_t)(h * 64 + ci) * 4096;
    char* lb = smem + bufi * 16384;
    #pragma unroll
    for (int i = 0; i < 2; ++i) {
      const int off = i * 4096 + tid * 16;
      gl_lds16((const char*)(a2f + tb) + off, lb + off);
    }
  };
  auto stage_v = [&](int bufi, int ci) {
    const size_t tb = (size_t)(h * 64 + ci) * 4096;
    char* lb = smem + bufi * 16384 + 8192;
    #pragma unroll
    for (int i = 0; i < 2; ++i) {
      const int off = i * 4096 + tid * 16;
      gl_lds16((const char*)(vf + tb) + off, lb + off);
    }
  };

  // helper: score chain — MUST be identical in both loops (bitwise-equal acc)
  auto scores = [&](const _Float16* base, f32x4 (&acc)[2]) {
    #pragma unroll
    for (int nt = 0; nt < 2; ++nt) acc[nt] = (f32x4){0.f, 0.f, 0.f, 0.f};
    #pragma unroll
    for (int kk = 0; kk < 2; ++kk)
      #pragma unroll
      for (int nt = 0; nt < 2; ++nt) {
        int eb = (wth * 32 + nt * 16 + c) * 64 + ((kk * 32 + g * 8) ^ ((c & 7) << 3));
        f16x8 bh = *(const f16x8*)(base + eb);
        acc[nt] = MFMA16F(a1f[kk], bh, acc[nt]);
      }
  };

  // ================= LOOP 1: row sums =================
  float rl[4] = {0.f, 0.f, 0.f, 0.f};

  stage_a2(0, 0);
  __syncthreads();

  #pragma unroll 1
  for (int ci = 0; ci < 64; ++ci) {
    if (ci < 63) stage_a2((ci + 1) & 1, ci + 1);

    const _Float16* base = (const _Float16*)(smem + (ci & 1) * 16384);
    f32x4 acc[2];
    scores(base, acc);

    const u32 mw0 = bmrow[ci * 64 + wth * 32 + c];
    const u32 mw1 = bmrow[ci * 64 + wth * 32 + 16 + c];
    #pragma unroll
    for (int nt = 0; nt < 2; ++nt) {
      const u32 mwv = nt ? mw1 : mw0;
      #pragma unroll
      for (int r = 0; r < 4; ++r) {
        float ex = EXP2F(acc[nt][r] * L2E);
        rl[r] += ((mwv >> (mbit + g * 4 + r)) & 1u) ? 0.f : ex;
      }
    }
    __syncthreads();
  }

  // reduce across c lanes (shfl within 16-lane groups), merge t-halves via LDS
  #pragma unroll
  for (int r = 0; r < 4; ++r) {
    float s = rl[r];
    #pragma unroll
    for (int off = 1; off < 16; off <<= 1) s += __shfl_xor(s, off);
    rl[r] = s;
  }
  __syncthreads();
  if (c == 0) {
    #pragma unroll
    for (int r = 0; r < 4; ++r) mll[w * 16 + g * 4 + r] = rl[r];
  }
  __syncthreads();
  float inv[4];
  #pragma unroll
  for (int r = 0; r < 4; ++r)
    inv[r] = 1.0f / (rl[r] + mll[(w ^ 1) * 16 + g * 4 + r]);

  // ================= LOOP 2: attn write + PV =================
  f32x4 oacc[4];
  #pragma unroll
  for (int dt = 0; dt < 4; ++dt) oacc[dt] = (f32x4){0.f, 0.f, 0.f, 0.f};

  float* aout = dout + (size_t)NHEAD * S_LEN * 64;
  _Float16* myatb = atb + w * 640;      // [16 rows][40] f16

  __syncthreads();
  stage_a2(0, 0);
  stage_v(0, 0);
  __syncthreads();

  #pragma unroll 1
  for (int ci = 0; ci < 64; ++ci) {
    if (ci < 63) { stage_a2((ci + 1) & 1, ci + 1); stage_v((ci + 1) & 1, ci + 1); }

    const _Float16* base = (const _Float16*)(smem + (ci & 1) * 16384);
    f32x4 acc[2];
    scores(base, acc);    // identical chain -> same values as loop 1

    const u32 mw0 = bmrow[ci * 64 + wth * 32 + c];
    const u32 mw1 = bmrow[ci * 64 + wth * 32 + 16 + c];
    float av[2][4];
    #pragma unroll
    for (int nt = 0; nt < 2; ++nt) {
      const u32 mwv = nt ? mw1 : mw0;
      #pragma unroll
      for (int r = 0; r < 4; ++r) {
        float ex = EXP2F(acc[nt][r] * L2E);
        av[nt][r] = ((mwv >> (mbit + g * 4 + r)) & 1u) ? 0.f : ex * inv[r];
      }
    }

    // transpose attn (f16) via per-wave LDS buf: [row][t], scatter write / b128 read
    #pragma unroll
    for (int nt = 0; nt < 2; ++nt)
      #pragma unroll
      for (int r = 0; r < 4; ++r)
        myatb[(g * 4 + r) * 40 + nt * 16 + c] = (_Float16)av[nt][r];

    asm volatile("" ::: "memory");

    f16x8 af = *(const f16x8*)(myatb + c * 40 + g * 8);

    // attn store from regs (fp32)
    {
      const size_t rb = (size_t)(h * S_LEN + sbase) * S_LEN + ci * 64 + wth * 32;
      #pragma unroll
      for (int nt = 0; nt < 2; ++nt)
        #pragma unroll
        for (int r = 0; r < 4; ++r)
          aout[rb + (size_t)(g * 4 + r) * S_LEN + nt * 16 + c] = av[nt][r];
    }

    // PV (normalized f16 attn x f16 v), K = this wave's 32 t
    #pragma unroll
    for (int dt = 0; dt < 4; ++dt) {
      int ve = 4096 + (dt * 16 + c) * 64 + ((wth * 32 + g * 8) ^ ((c & 7) << 3));
      f16x8 bv = *(const f16x8*)(base + ve);
      oacc[dt] = MFMA16F(af, bv, oacc[dt]);
    }

    __syncthreads();
  }

  // epilogue: merge t-half partials, store out
  __syncthreads();
  float* outx = (float*)smem;           // [2 wsr][16][66] f32 = 8448 B
  if (wth == 1) {
    #pragma unroll
    for (int dt = 0; dt < 4; ++dt)
      #pragma unroll
      for (int r = 0; r < 4; ++r)
        outx[wsr * 1056 + (g * 4 + r) * 66 + dt * 16 + c] = oacc[dt][r];
  }
  __syncthreads();
  if (wth == 0) {
    #pragma unroll
    for (int dt = 0; dt < 4; ++dt)
      #pragma unroll
      for (int r = 0; r < 4; ++r) {
        float vv = oacc[dt][r] + outx[wsr * 1056 + (g * 4 + r) * 66 + dt * 16 + c];
        int s = sbase + g * 4 + r;
        dout[(size_t)(h * S_LEN + s) * 64 + dt * 16 + c] = vv;
      }
  }
}

extern "C" void kernel_launch(void* const* d_in, const int* in_sizes, int n_in,
                              void* d_out, int out_size, void* d_ws, size_t ws_size,
                              hipStream_t stream) {
  (void)in_sizes; (void)n_in; (void)out_size; (void)ws_size;
  const float* v    = (const float*)d_in[0];
  const float* A1   = (const float*)d_in[1];
  const float* A2   = (const float*)d_in[2];
  const int*   mask = (const int*)d_in[3];
  float* out = (float*)d_out;
  char* ws = (char*)d_ws;

  _Float16* a2f = (_Float16*)(ws + WS_A2F);
  _Float16* vf  = (_Float16*)(ws + WS_VF);
  u32* bmT      = (u32*)(ws + WS_BM);

  pk_mask    <<<2048, 256, 0, stream>>>(mask, bmT);
  pk_tsplit16<<<512,  256, 0, stream>>>(A2, a2f, 64, 4096);   // A2[f][t] -> [t][f]
  pk_tsplit16<<<512,  256, 0, stream>>>(v,  vf,  4096, 64);   // v[t][d]  -> [d][t]
  fattn_fused<<<1024, 256, 0, stream>>>(A1, a2f, vf, bmT, out);
}